// Round 1
// baseline (34976.917 us; speedup 1.0000x reference)
//
#include <hip/hip_runtime.h>
#include <math.h>
#include <float.h>

#define KE 8192        // number of edges
#define NPF 3072       // floats per edge (1024 * 3)
#define NT 1024        // threads in chain kernel
#define EPT 8          // edges per thread (KE / NT)
#define TOPK_N 10

// IEEE distance, no fma contraction: matches numpy ((dx*dx + dy*dy) + dz*dz) then sqrt
__device__ __forceinline__ float dist3(float ax, float ay, float az,
                                       float bx, float by, float bz) {
#pragma clang fp contract(off)
  float dx = ax - bx, dy = ay - by, dz = az - bz;
  float s = (dx * dx + dy * dy) + dz * dz;
  return sqrtf(s);
}

extern "C" __global__ void __launch_bounds__(NT)
chain_kernel(const float* __restrict__ edges, float* __restrict__ tail,
             int* __restrict__ ws_order, int* __restrict__ ws_flip)
{
  const int tid = threadIdx.x;
  const int lane = tid & 63;
  const int wid = tid >> 6;

  __shared__ float s_v[16];
  __shared__ int   s_i[16];
  __shared__ int   s_f[16];
  __shared__ float s_nx[16], s_ny[16], s_nz[16];
  __shared__ float s_cur[3];
  __shared__ int   s_j;
  __shared__ float s_s0[3], s_e0[3];
  __shared__ float s_first[3];
  __shared__ float s_m1[16], s_m2[16];

  // ---- load endpoints of my 8 edges into registers ----
  float sx[EPT], sy[EPT], sz[EPT], ex[EPT], ey[EPT], ez[EPT];
#pragma unroll
  for (int e = 0; e < EPT; ++e) {
    const float* p = edges + (size_t)(tid * EPT + e) * NPF;
    sx[e] = p[0];       sy[e] = p[1];       sz[e] = p[2];
    ex[e] = p[NPF - 3]; ey[e] = p[NPF - 2]; ez[e] = p[NPF - 1];
  }

  // ---- lengths; top-10 longest; start_index = max index among them ----
  // (reference's score = min-dist-to-all-points - 1e-9*idx, and the min dist
  //  is exactly 0 since the candidate's own endpoints are in the point set,
  //  so argmin(score) picks the LARGEST candidate index)
  float len[EPT];
#pragma unroll
  for (int e = 0; e < EPT; ++e)
    len[e] = dist3(ex[e], ey[e], ez[e], sx[e], sy[e], sz[e]);

  unsigned tk = 0;          // bits of my edges already taken into top-k
  int start_index = -1;
  for (int r = 0; r < TOPK_N; ++r) {
    float bv = -INFINITY; int bi = 0x7fffffff;
#pragma unroll
    for (int e = 0; e < EPT; ++e) {
      if ((tk >> e) & 1) continue;
      if (len[e] > bv) { bv = len[e]; bi = tid * EPT + e; }
    }
    for (int m = 1; m < 64; m <<= 1) {
      float v2 = __shfl_xor(bv, m); int i2 = __shfl_xor(bi, m);
      if (v2 > bv || (v2 == bv && i2 < bi)) { bv = v2; bi = i2; }
    }
    if (lane == 0) { s_v[wid] = bv; s_i[wid] = bi; }
    __syncthreads();
    if (wid == 0) {
      int sl = lane & 15;
      bv = s_v[sl]; bi = s_i[sl];
      for (int m = 1; m < 16; m <<= 1) {
        float v2 = __shfl_xor(bv, m); int i2 = __shfl_xor(bi, m);
        if (v2 > bv || (v2 == bv && i2 < bi)) { bv = v2; bi = i2; }
      }
      if (lane == 0) s_j = bi;
    }
    __syncthreads();
    int sel = s_j;
    if ((sel >> 3) == tid) tk |= 1u << (sel & 7);
    if (sel > start_index) start_index = sel;
  }
  __syncthreads();

  // ---- publish s0 / e0 ----
  if (tid == (start_index >> 3)) {
    int e = start_index & 7;
    s_s0[0] = sx[e]; s_s0[1] = sy[e]; s_s0[2] = sz[e];
    s_e0[0] = ex[e]; s_e0[1] = ey[e]; s_e0[2] = ez[e];
  }
  __syncthreads();
  float s0x = s_s0[0], s0y = s_s0[1], s0z = s_s0[2];
  float e0x = s_e0[0], e0y = s_e0[1], e0z = s_e0[2];

  // ---- use_flip0: min dist from s0 vs e0 to all OTHER edges' endpoints ----
  float m1 = INFINITY, m2 = INFINITY;
#pragma unroll
  for (int e = 0; e < EPT; ++e) {
    int k = tid * EPT + e;
    if (k == start_index) continue;
    float a = dist3(s0x, s0y, s0z, sx[e], sy[e], sz[e]);
    float b = dist3(s0x, s0y, s0z, ex[e], ey[e], ez[e]);
    m1 = fminf(m1, fminf(a, b));
    float c = dist3(e0x, e0y, e0z, sx[e], sy[e], sz[e]);
    float d = dist3(e0x, e0y, e0z, ex[e], ey[e], ez[e]);
    m2 = fminf(m2, fminf(c, d));
  }
  for (int m = 1; m < 64; m <<= 1) {
    m1 = fminf(m1, __shfl_xor(m1, m));
    m2 = fminf(m2, __shfl_xor(m2, m));
  }
  if (lane == 0) { s_m1[wid] = m1; s_m2[wid] = m2; }
  __syncthreads();
  if (wid == 0) {
    int sl = lane & 15;
    m1 = s_m1[sl]; m2 = s_m2[sl];
    for (int m = 1; m < 16; m <<= 1) {
      m1 = fminf(m1, __shfl_xor(m1, m));
      m2 = fminf(m2, __shfl_xor(m2, m));
    }
    if (lane == 0) {
      int flip0 = (m1 < m2) ? 1 : 0;
      s_cur[0]   = flip0 ? s0x : e0x;
      s_cur[1]   = flip0 ? s0y : e0y;
      s_cur[2]   = flip0 ? s0z : e0z;
      s_first[0] = flip0 ? e0x : s0x;
      s_first[1] = flip0 ? e0y : s0y;
      s_first[2] = flip0 ? e0z : s0z;
      tail[0]      = (float)start_index;   // order[0]
      tail[KE]     = (float)flip0;         // flips[0]
      ws_order[0] = start_index;
      ws_flip[0]  = flip0;
    }
  }
  __syncthreads();

  unsigned used = 0;
  if ((start_index >> 3) == tid) used = 1u << (start_index & 7);
  float cx = s_cur[0], cy = s_cur[1], cz = s_cur[2];

  float* ord_f = tail;
  float* flp_f = tail + KE;
  float* dst_f = tail + 2 * KE;

  // ---- greedy chain: 8191 sequential argmin steps ----
  for (int t = 0; t < KE - 1; ++t) {
    float bv = INFINITY; int bi = 0x7fffffff; int bf = 0;
    float bnx = 0.f, bny = 0.f, bnz = 0.f;
#pragma unroll
    for (int e = 0; e < EPT; ++e) {
      if ((used >> e) & 1) continue;
      float da = dist3(cx, cy, cz, sx[e], sy[e], sz[e]);
      float db = dist3(cx, cy, cz, ex[e], ey[e], ez[e]);
      float v = fminf(da, db);
      if (v < bv) {
        bv = v; bi = tid * EPT + e;
        int fl = (da > db) ? 1 : 0;
        bf = fl;
        bnx = fl ? sx[e] : ex[e];
        bny = fl ? sy[e] : ey[e];
        bnz = fl ? sz[e] : ez[e];
      }
    }
    for (int m = 1; m < 64; m <<= 1) {
      float v2 = __shfl_xor(bv, m); int i2 = __shfl_xor(bi, m);
      int   f2 = __shfl_xor(bf, m);
      float x2 = __shfl_xor(bnx, m), y2 = __shfl_xor(bny, m), z2 = __shfl_xor(bnz, m);
      if (v2 < bv || (v2 == bv && i2 < bi)) {
        bv = v2; bi = i2; bf = f2; bnx = x2; bny = y2; bnz = z2;
      }
    }
    if (lane == 0) {
      s_v[wid] = bv; s_i[wid] = bi; s_f[wid] = bf;
      s_nx[wid] = bnx; s_ny[wid] = bny; s_nz[wid] = bnz;
    }
    __syncthreads();
    if (wid == 0) {
      int sl = lane & 15;
      bv = s_v[sl]; bi = s_i[sl]; bf = s_f[sl];
      bnx = s_nx[sl]; bny = s_ny[sl]; bnz = s_nz[sl];
      for (int m = 1; m < 16; m <<= 1) {
        float v2 = __shfl_xor(bv, m); int i2 = __shfl_xor(bi, m);
        int   f2 = __shfl_xor(bf, m);
        float x2 = __shfl_xor(bnx, m), y2 = __shfl_xor(bny, m), z2 = __shfl_xor(bnz, m);
        if (v2 < bv || (v2 == bv && i2 < bi)) {
          bv = v2; bi = i2; bf = f2; bnx = x2; bny = y2; bnz = z2;
        }
      }
      if (lane == 0) {
        s_j = bi;
        s_cur[0] = bnx; s_cur[1] = bny; s_cur[2] = bnz;
        ord_f[t + 1] = (float)bi;
        flp_f[t + 1] = (float)bf;
        dst_f[t]     = bv;
        ws_order[t + 1] = bi;
        ws_flip[t + 1]  = bf;
      }
    }
    __syncthreads();
    int j = s_j;
    if ((j >> 3) == tid) used |= 1u << (j & 7);
    cx = s_cur[0]; cy = s_cur[1]; cz = s_cur[2];
  }

  // closing distance: ||final_cur_end - first_point||
  if (tid == 0) {
    dst_f[KE - 1] = dist3(s_cur[0], s_cur[1], s_cur[2],
                          s_first[0], s_first[1], s_first[2]);
  }
}

extern "C" __global__ void __launch_bounds__(256)
gather_kernel(const float* __restrict__ edges, const int* __restrict__ ws_order,
              const int* __restrict__ ws_flip, float* __restrict__ out)
{
  int idx = blockIdx.x * 256 + threadIdx.x;   // < 25165824, fits int
  int i = idx / NPF;
  int f = idx - i * NPF;
  int o  = ws_order[i];
  int fl = ws_flip[i];
  int r = f / 3;
  int c = f - r * 3;
  int srcf = fl ? ((1023 - r) * 3 + c) : f;
  out[idx] = edges[o * NPF + srcf];
}

extern "C" void kernel_launch(void* const* d_in, const int* in_sizes, int n_in,
                              void* d_out, int out_size, void* d_ws, size_t ws_size,
                              hipStream_t stream) {
  (void)in_sizes; (void)n_in; (void)out_size; (void)ws_size;
  const float* edges = (const float*)d_in[0];
  float* out  = (float*)d_out;
  float* tail = out + (size_t)KE * NPF;        // order | flips | distances
  int* ws_order = (int*)d_ws;
  int* ws_flip  = ws_order + KE;

  hipLaunchKernelGGL(chain_kernel, dim3(1), dim3(NT), 0, stream,
                     edges, tail, ws_order, ws_flip);
  hipLaunchKernelGGL(gather_kernel, dim3((KE * NPF) / 256), dim3(256), 0, stream,
                     edges, ws_order, ws_flip, out);
}

// Round 2
// 17091.695 us; speedup vs baseline: 2.0464x; 2.0464x over previous
//
#include <hip/hip_runtime.h>
#include <math.h>
#include <float.h>

#define KE 8192        // number of edges
#define NPF 3072       // floats per edge (1024 * 3)
#define NT 1024        // threads in chain kernel
#define EPT 8          // edges per thread (KE / NT)
#define TOPK_N 10

typedef unsigned long long u64;

// IEEE squared distance, no fma contraction: matches numpy (dx*dx + dy*dy) + dz*dz
__device__ __forceinline__ float dist2(float ax, float ay, float az,
                                       float bx, float by, float bz) {
#pragma clang fp contract(off)
  float dx = ax - bx, dy = ay - by, dz = az - bz;
  float s = (dx * dx + dy * dy) + dz * dz;
  return s;
}

__device__ __forceinline__ float dist3(float ax, float ay, float az,
                                       float bx, float by, float bz) {
  return sqrtf(dist2(ax, ay, az, bx, by, bz));
}

extern "C" __global__ void __launch_bounds__(NT)
chain_kernel(const float* __restrict__ edges, float* __restrict__ tail,
             int* __restrict__ ws_order, int* __restrict__ ws_flip)
{
  const int tid = threadIdx.x;
  const int lane = tid & 63;
  const int wid = tid >> 6;

  __shared__ u64   s_part[16];
  __shared__ u64   s_win;
  __shared__ float s_v[16];
  __shared__ int   s_i[16];
  __shared__ float s_cur[3];
  __shared__ int   s_j;
  __shared__ float s_s0[3], s_e0[3];
  __shared__ float s_first[3];
  __shared__ float s_m1[16], s_m2[16];

  // ---- load endpoints of my 8 edges into registers ----
  float sx[EPT], sy[EPT], sz[EPT], ex[EPT], ey[EPT], ez[EPT];
#pragma unroll
  for (int e = 0; e < EPT; ++e) {
    const float* p = edges + (size_t)(tid * EPT + e) * NPF;
    sx[e] = p[0];       sy[e] = p[1];       sz[e] = p[2];
    ex[e] = p[NPF - 3]; ey[e] = p[NPF - 2]; ez[e] = p[NPF - 1];
  }

  // ---- lengths; top-10 longest; start_index = max index among them ----
  // (reference's score is exactly 0 at each candidate minus 1e-9*idx, so
  //  argmin(score) picks the LARGEST candidate index among the top-10)
  // Exact sqrt here: stable-argsort tie semantics must match bit-for-bit.
  float len[EPT];
#pragma unroll
  for (int e = 0; e < EPT; ++e)
    len[e] = dist3(ex[e], ey[e], ez[e], sx[e], sy[e], sz[e]);

  unsigned tk = 0;          // bits of my edges already taken into top-k
  int start_index = -1;
  for (int r = 0; r < TOPK_N; ++r) {
    float bv = -INFINITY; int bi = 0x7fffffff;
#pragma unroll
    for (int e = 0; e < EPT; ++e) {
      if ((tk >> e) & 1) continue;
      if (len[e] > bv) { bv = len[e]; bi = tid * EPT + e; }
    }
    for (int m = 1; m < 64; m <<= 1) {
      float v2 = __shfl_xor(bv, m); int i2 = __shfl_xor(bi, m);
      if (v2 > bv || (v2 == bv && i2 < bi)) { bv = v2; bi = i2; }
    }
    if (lane == 0) { s_v[wid] = bv; s_i[wid] = bi; }
    __syncthreads();
    if (wid == 0) {
      int sl = lane & 15;
      bv = s_v[sl]; bi = s_i[sl];
      for (int m = 1; m < 16; m <<= 1) {
        float v2 = __shfl_xor(bv, m); int i2 = __shfl_xor(bi, m);
        if (v2 > bv || (v2 == bv && i2 < bi)) { bv = v2; bi = i2; }
      }
      if (lane == 0) s_j = bi;
    }
    __syncthreads();
    int sel = s_j;
    if ((sel >> 3) == tid) tk |= 1u << (sel & 7);
    if (sel > start_index) start_index = sel;
    __syncthreads();
  }

  // ---- publish s0 / e0 ----
  if (tid == (start_index >> 3)) {
    int e = start_index & 7;
    float osx = sx[0], osy = sy[0], osz = sz[0];
    float oex = ex[0], oey = ey[0], oez = ez[0];
#pragma unroll
    for (int k = 1; k < EPT; ++k) {
      if (e == k) {
        osx = sx[k]; osy = sy[k]; osz = sz[k];
        oex = ex[k]; oey = ey[k]; oez = ez[k];
      }
    }
    s_s0[0] = osx; s_s0[1] = osy; s_s0[2] = osz;
    s_e0[0] = oex; s_e0[1] = oey; s_e0[2] = oez;
  }
  __syncthreads();
  float s0x = s_s0[0], s0y = s_s0[1], s0z = s_s0[2];
  float e0x = s_e0[0], e0y = s_e0[1], e0z = s_e0[2];

  // ---- use_flip0: min dist from s0 vs e0 to all OTHER edges' endpoints ----
  // squared-space mins; sqrt(min) == min(sqrt) exactly (monotone), so the
  // final comparison is bit-exact vs the reference.
  float m1 = INFINITY, m2 = INFINITY;
#pragma unroll
  for (int e = 0; e < EPT; ++e) {
    int k = tid * EPT + e;
    float a = dist2(s0x, s0y, s0z, sx[e], sy[e], sz[e]);
    float b = dist2(s0x, s0y, s0z, ex[e], ey[e], ez[e]);
    float c = dist2(e0x, e0y, e0z, sx[e], sy[e], sz[e]);
    float d = dist2(e0x, e0y, e0z, ex[e], ey[e], ez[e]);
    float v1 = fminf(a, b), v2 = fminf(c, d);
    if (k == start_index) { v1 = INFINITY; v2 = INFINITY; }
    m1 = fminf(m1, v1);
    m2 = fminf(m2, v2);
  }
  for (int m = 1; m < 64; m <<= 1) {
    m1 = fminf(m1, __shfl_xor(m1, m));
    m2 = fminf(m2, __shfl_xor(m2, m));
  }
  if (lane == 0) { s_m1[wid] = m1; s_m2[wid] = m2; }
  __syncthreads();
  if (wid == 0) {
    int sl = lane & 15;
    m1 = s_m1[sl]; m2 = s_m2[sl];
    for (int m = 1; m < 16; m <<= 1) {
      m1 = fminf(m1, __shfl_xor(m1, m));
      m2 = fminf(m2, __shfl_xor(m2, m));
    }
    if (lane == 0) {
      int flip0 = (sqrtf(m1) < sqrtf(m2)) ? 1 : 0;
      s_cur[0]   = flip0 ? s0x : e0x;
      s_cur[1]   = flip0 ? s0y : e0y;
      s_cur[2]   = flip0 ? s0z : e0z;
      s_first[0] = flip0 ? e0x : s0x;
      s_first[1] = flip0 ? e0y : s0y;
      s_first[2] = flip0 ? e0z : s0z;
      tail[0]      = (float)start_index;   // order[0]
      tail[KE]     = (float)flip0;         // flips[0]
      ws_order[0] = start_index;
      ws_flip[0]  = flip0;
    }
  }
  __syncthreads();

  unsigned used = 0;
  if ((start_index >> 3) == tid) used = 1u << (start_index & 7);
  float cx = s_cur[0], cy = s_cur[1], cz = s_cur[2];

  float* ord_f = tail;
  float* flp_f = tail + KE;
  float* dst_f = tail + 2 * KE;

  // ---- greedy chain: 8191 sequential argmin steps ----
  // key = (d^2 bits << 32) | edge_index  -> u64 min == (min d^2, lowest idx)
  for (int t = 0; t < KE - 1; ++t) {
    u64 best = ~0ull;
#pragma unroll
    for (int e = 0; e < EPT; ++e) {
      float da2 = dist2(cx, cy, cz, sx[e], sy[e], sz[e]);
      float db2 = dist2(cx, cy, cz, ex[e], ey[e], ez[e]);
      float v = fminf(da2, db2);
      u64 key = ((u64)__float_as_uint(v) << 32) | (unsigned)(tid * EPT + e);
      key = ((used >> e) & 1) ? ~0ull : key;
      best = (key < best) ? key : best;
    }
#pragma unroll
    for (int m = 1; m < 64; m <<= 1) {
      u64 o = __shfl_xor(best, m);
      best = (o < best) ? o : best;
    }
    if (lane == 0) s_part[wid] = best;
    __syncthreads();
    if (wid == 0) {
      u64 b = s_part[lane & 15];
#pragma unroll
      for (int m = 1; m < 16; m <<= 1) {
        u64 o = __shfl_xor(b, m);
        b = (o < b) ? o : b;
      }
      if (lane == 0) s_win = b;
    }
    __syncthreads();
    u64 w = s_win;
    int j = (int)(w & 0xffffffffu);
    if (tid == (j >> 3)) {       // owner of winning edge publishes everything
      int e = j & 7;
      float osx = sx[0], osy = sy[0], osz = sz[0];
      float oex = ex[0], oey = ey[0], oez = ez[0];
#pragma unroll
      for (int k = 1; k < EPT; ++k) {
        if (e == k) {
          osx = sx[k]; osy = sy[k]; osz = sz[k];
          oex = ex[k]; oey = ey[k]; oez = ez[k];
        }
      }
      float da2 = dist2(cx, cy, cz, osx, osy, osz);
      float db2 = dist2(cx, cy, cz, oex, oey, oez);
      // exact reference semantics: flip = sqrt(da2) > sqrt(db2)
      int fl = (sqrtf(da2) > sqrtf(db2)) ? 1 : 0;
      s_cur[0] = fl ? osx : oex;
      s_cur[1] = fl ? osy : oey;
      s_cur[2] = fl ? osz : oez;
      ord_f[t + 1] = (float)j;
      flp_f[t + 1] = (float)fl;
      dst_f[t]     = sqrtf(__uint_as_float((unsigned)(w >> 32)));
      ws_order[t + 1] = j;
      ws_flip[t + 1]  = fl;
      used |= 1u << e;
    }
    __syncthreads();
    cx = s_cur[0]; cy = s_cur[1]; cz = s_cur[2];
  }

  // closing distance: ||final_cur_end - first_point||
  if (tid == 0) {
    dst_f[KE - 1] = dist3(s_cur[0], s_cur[1], s_cur[2],
                          s_first[0], s_first[1], s_first[2]);
  }
}

extern "C" __global__ void __launch_bounds__(256)
gather_kernel(const float* __restrict__ edges, const int* __restrict__ ws_order,
              const int* __restrict__ ws_flip, float* __restrict__ out)
{
  int idx = blockIdx.x * 256 + threadIdx.x;   // < 25165824, fits int
  int i = idx / NPF;
  int f = idx - i * NPF;
  int o  = ws_order[i];
  int fl = ws_flip[i];
  int r = f / 3;
  int c = f - r * 3;
  int srcf = fl ? ((1023 - r) * 3 + c) : f;
  out[idx] = edges[o * NPF + srcf];
}

extern "C" void kernel_launch(void* const* d_in, const int* in_sizes, int n_in,
                              void* d_out, int out_size, void* d_ws, size_t ws_size,
                              hipStream_t stream) {
  (void)in_sizes; (void)n_in; (void)out_size; (void)ws_size;
  const float* edges = (const float*)d_in[0];
  float* out  = (float*)d_out;
  float* tail = out + (size_t)KE * NPF;        // order | flips | distances
  int* ws_order = (int*)d_ws;
  int* ws_flip  = ws_order + KE;

  hipLaunchKernelGGL(chain_kernel, dim3(1), dim3(NT), 0, stream,
                     edges, tail, ws_order, ws_flip);
  hipLaunchKernelGGL(gather_kernel, dim3((KE * NPF) / 256), dim3(256), 0, stream,
                     edges, ws_order, ws_flip, out);
}